// Round 8
// baseline (152.749 us; speedup 1.0000x reference)
//
#include <hip/hip_runtime.h>
#include <hip/hip_bf16.h>

#define CIN 256
#define NV 4096
#define NHEAD 8
#define HD 32
#define NSPLIT 2
#define KSPAN (NV / NSPLIT)
#define LOG2E 1.44269504088896340736f

typedef __attribute__((ext_vector_type(8))) short short8;
typedef __attribute__((ext_vector_type(4))) float f32x4;

static __device__ __forceinline__ unsigned short f2bf(float f) {
    union { float f; unsigned u; } v; v.f = f;
    unsigned r = v.u + 0x7fffu + ((v.u >> 16) & 1u);  // RNE
    return (unsigned short)(r >> 16);
}
// pack two fp32 -> packed bf16 pair (truncating): lo from x0, hi from x1
static __device__ __forceinline__ unsigned pk_bf2(float x0, float x1) {
    return __builtin_amdgcn_perm(__float_as_uint(x1), __float_as_uint(x0),
                                 0x07060302u);
}

// ---------------------------------------------------------------------------
// Kernel 1: fused QKV projection. Block stages x-transpose (bf16) in LDS ONCE,
// then loops over all 4 m-tiles (256 output rows). Weights converted inline.
//   Q,K -> [h][n][c] bf16 (Q pre-scaled by log2e) ; V -> [c][n] bf16
// grid (NV/64, 3), block 256.
// ---------------------------------------------------------------------------
__global__ __launch_bounds__(256) void qkv_fused(
    const float* __restrict__ x,
    const float* __restrict__ wq, const float* __restrict__ bq,
    const float* __restrict__ wk, const float* __restrict__ bk,
    const float* __restrict__ wv, const float* __restrict__ bv,
    unsigned short* __restrict__ Qbf, unsigned short* __restrict__ Kbf,
    unsigned short* __restrict__ Vbf)
{
    const int which = blockIdx.y;
    const float* Wp = (which == 0) ? wq : (which == 1) ? wk : wv;
    const float* Bp = (which == 0) ? bq : (which == 1) ? bk : bv;
    const int cbase = (which == 0) ? 0 : CIN;

    const int n0 = blockIdx.x * 64;
    const int t = threadIdx.x;

    __shared__ unsigned short Xs[64][264];  // [n][c], pitch 264 (16B mult)

    // stage: x [c][n] fp32 -> Xs [n][c] bf16 (coalesced reads)
    {
        const int n = t & 63, cg = t >> 6;
#pragma unroll 4
        for (int cc = 0; cc < 64; cc += 2) {
            const int c = cg * 64 + cc;
            size_t off = (size_t)(cbase + c) * NV + n0 + n;
            *(unsigned*)&Xs[n][c] = pk_bf2(x[off], x[off + NV]);
        }
    }
    __syncthreads();

    const int w = t >> 6;
    const int lane = t & 63;
    const int ln = lane & 15;
    const int quad = lane >> 4;

    for (int mt = 0; mt < 4; ++mt) {
        const int m0 = mt * 64;
        const int M = m0 + w * 16 + ln;

        f32x4 acc[4] = {};
        for (int k0 = 0; k0 < 256; k0 += 32) {
            float4 a0 = *(const float4*)&Wp[(size_t)M * 256 + k0 + quad * 8];
            float4 a1 = *(const float4*)&Wp[(size_t)M * 256 + k0 + quad * 8 + 4];
            short8 a;
            unsigned* au = (unsigned*)&a;
            au[0] = pk_bf2(a0.x, a0.y);
            au[1] = pk_bf2(a0.z, a0.w);
            au[2] = pk_bf2(a1.x, a1.y);
            au[3] = pk_bf2(a1.z, a1.w);
            short8 b[4];
#pragma unroll
            for (int nt = 0; nt < 4; ++nt)
                b[nt] = *(const short8*)&Xs[nt * 16 + ln][k0 + quad * 8];
            if (which == 2) {
#pragma unroll
                for (int nt = 0; nt < 4; ++nt)
                    acc[nt] = __builtin_amdgcn_mfma_f32_16x16x32_bf16(
                        b[nt], a, acc[nt], 0, 0, 0);
            } else {
#pragma unroll
                for (int nt = 0; nt < 4; ++nt)
                    acc[nt] = __builtin_amdgcn_mfma_f32_16x16x32_bf16(
                        a, b[nt], acc[nt], 0, 0, 0);
            }
        }

        if (which == 2) {
            // lane holds V[n=n0+nt*16+quad*4+r][ch=m0+w*16+ln]
            const int ch = m0 + w * 16 + ln;
            const float bias = Bp[ch];
#pragma unroll
            for (int nt = 0; nt < 4; ++nt) {
                unsigned short pk[4];
#pragma unroll
                for (int r = 0; r < 4; ++r) pk[r] = f2bf(acc[nt][r] + bias);
                *(uint2*)&Vbf[(size_t)ch * NV + n0 + nt * 16 + quad * 4] =
                    *(uint2*)pk;
            }
        } else {
            // lane holds D[m=m0+w*16+quad*4+r][n=n0+nt*16+ln]; RoPE + pack
            unsigned short* dst = (which == 0) ? Qbf : Kbf;
            const int mb = m0 + w * 16 + quad * 4;
            const int h = mb >> 5;
            const int cb = mb & 31;
            const float qscale = (which == 0) ? LOG2E : 1.0f;
            float bias[4], invf[4];
#pragma unroll
            for (int r = 0; r < 4; ++r) {
                bias[r] = Bp[mb + r];
                invf[r] =
                    __powf(10000.0f, -(float)((cb + r) & 15) * (1.0f / 16.0f));
            }
            const bool use_sin = (cb < 16);
#pragma unroll
            for (int nt = 0; nt < 4; ++nt) {
                const int n = n0 + nt * 16 + ln;
                const float pos = (float)n * (2.0f / 4095.0f) - 1.0f;
                unsigned short pk[4];
#pragma unroll
                for (int r = 0; r < 4; ++r) {
                    float ang = pos * invf[r];
                    float f = (use_sin ? __sinf(ang) : __cosf(ang)) * qscale;
                    pk[r] = f2bf((acc[nt][r] + bias[r]) * f);
                }
                *(uint2*)&dst[((size_t)h * NV + n) * HD + cb] = *(uint2*)pk;
            }
        }
    }
}

// ---------------------------------------------------------------------------
// Kernel 2: attention. bf16 MFMA, split-K, register-resident P, async
// double-buffered V staging. Denominators via ones-vector MFMA. Q is
// log2e-pre-scaled -> raw v_exp_f32 (__builtin_amdgcn_exp2f).
// grid (NV/64, NHEAD, NSPLIT), block 256.
// ---------------------------------------------------------------------------
__global__ __launch_bounds__(256, 4) void attn_mfma(
    const unsigned short* __restrict__ Qbf,
    const unsigned short* __restrict__ Kbf,
    const unsigned short* __restrict__ Vbf,
    float* __restrict__ Opart, float* __restrict__ Lpart)
{
    const int h = blockIdx.y;
    const int q0 = blockIdx.x * 64;
    const int z = blockIdx.z;
    const int kbase = z * KSPAN;
    const int t = threadIdx.x;
    const int w = t >> 6;
    const int lane = t & 63;
    const int ln = lane & 15;
    const int quad = lane >> 4;

    __shared__ __align__(16) unsigned short Vs[2][2048];  // 2 x 4KB V tiles

    const short8 qa = *(const short8*)
        &Qbf[((size_t)h * NV + q0 + w * 16 + ln) * HD + quad * 8];

    const unsigned short* Kh = Kbf + (size_t)h * NV * HD;
    const unsigned short* Vh = Vbf + (size_t)h * HD * NV;

    const int c_st = (w << 3) + (lane >> 3);
    const int gr_st = (lane & 7) ^ (c_st & 7);
    const unsigned short* gsrc = Vh + (size_t)c_st * NV + gr_st * 8;
    unsigned short* lds0 = &Vs[0][(size_t)(w * 64 + lane) * 8];
    unsigned short* lds1 = &Vs[1][(size_t)(w * 64 + lane) * 8];

    f32x4 oacc[2] = {};
    f32x4 lacc = {};
    const short vone = (short)0x3F80;
    const short8 vones = {vone, vone, vone, vone, vone, vone, vone, vone};

    __builtin_amdgcn_global_load_lds(
        (const __attribute__((address_space(1))) unsigned int*)(gsrc + kbase),
        (__attribute__((address_space(3))) unsigned int*)lds0, 16, 0, 0);
    short8 kf[4];
#pragma unroll
    for (int ct = 0; ct < 4; ++ct)
        kf[ct] = *(const short8*)
            &Kh[(size_t)(kbase + ct * 16 + ln) * HD + quad * 8];
    __syncthreads();

    for (int i = 0; i < KSPAN / 64; ++i) {
        const int kb = kbase + i * 64;
        const int buf = i & 1;

        if (i + 1 < KSPAN / 64) {
            __builtin_amdgcn_global_load_lds(
                (const __attribute__((address_space(1))) unsigned int*)(gsrc + kb + 64),
                (__attribute__((address_space(3))) unsigned int*)(buf ? lds0 : lds1),
                16, 0, 0);
        }
        const int kbn = kbase + (((i + 1) & (KSPAN / 64 - 1)) * 64);
        short8 kfn[4];
#pragma unroll
        for (int ct = 0; ct < 4; ++ct)
            kfn[ct] = *(const short8*)
                &Kh[(size_t)(kbn + ct * 16 + ln) * HD + quad * 8];

        // S^T: lane holds S'[q=ln][key = kb + 16ct + quad*4 + r] (log2-scaled)
        f32x4 s[4];
#pragma unroll
        for (int ct = 0; ct < 4; ++ct) {
            f32x4 z4 = {0.f, 0.f, 0.f, 0.f};
            s[ct] = __builtin_amdgcn_mfma_f32_16x16x32_bf16(kf[ct], qa, z4,
                                                            0, 0, 0);
        }

        float p[4][4];
#pragma unroll
        for (int ct = 0; ct < 4; ++ct)
#pragma unroll
            for (int r = 0; r < 4; ++r)
                p[ct][r] = __builtin_amdgcn_exp2f(s[ct][r]);

#pragma unroll
        for (int h2 = 0; h2 < 2; ++h2) {
            short8 pa;
            unsigned* pau = (unsigned*)&pa;
            pau[0] = pk_bf2(p[2 * h2][0], p[2 * h2][1]);
            pau[1] = pk_bf2(p[2 * h2][2], p[2 * h2][3]);
            pau[2] = pk_bf2(p[2 * h2 + 1][0], p[2 * h2 + 1][1]);
            pau[3] = pk_bf2(p[2 * h2 + 1][2], p[2 * h2 + 1][3]);
            // denominators: rowsum(P) with the SAME packed weights
            lacc = __builtin_amdgcn_mfma_f32_16x16x32_bf16(pa, vones, lacc,
                                                           0, 0, 0);
#pragma unroll
            for (int ctile = 0; ctile < 2; ++ctile) {
                const int cA = ctile * 16 + ln;
                short8 vb;
                unsigned* vbu = (unsigned*)&vb;
#pragma unroll
                for (int g = 0; g < 2; ++g) {
                    const int gr = h2 * 4 + g * 2 + (quad >> 1);
                    const int sg = gr ^ (ln & 7);
                    uint2 vv = *(const uint2*)
                        &Vs[buf][cA * 64 + sg * 8 + (quad & 1) * 4];
                    vbu[g * 2 + 0] = vv.x;
                    vbu[g * 2 + 1] = vv.y;
                }
                oacc[ctile] = __builtin_amdgcn_mfma_f32_16x16x32_bf16(
                    pa, vb, oacc[ctile], 0, 0, 0);
            }
        }

#pragma unroll
        for (int ct = 0; ct < 4; ++ct) kf[ct] = kfn[ct];
        __syncthreads();
    }

    float* Oz = Opart + (size_t)z * CIN * NV;
    float* Lz = Lpart + (size_t)z * NHEAD * NV;
    if (ln == 0) {
#pragma unroll
        for (int r = 0; r < 4; ++r)
            Lz[(size_t)h * NV + q0 + w * 16 + quad * 4 + r] = lacc[r];
    }
#pragma unroll
    for (int ctile = 0; ctile < 2; ++ctile)
        *(f32x4*)&Oz[(size_t)(h * HD + ctile * 16 + ln) * NV + q0 + w * 16 +
                     quad * 4] = oacc[ctile];
}

// ---------------------------------------------------------------------------
// Kernel 3: fused combine + output projection. Block stages
//   Y[n][c] = (O0+O1)[c][n]/(l0+l1) + qf[c][n]  (bf16, LDS) ONCE, then loops
//   over 4 m-tiles (its 256 of the 512 output rows).
// grid (NV/64, 2), block 256.
// ---------------------------------------------------------------------------
__global__ __launch_bounds__(256) void out_fused(
    const float* __restrict__ x,
    const float* __restrict__ Opart, const float* __restrict__ Lpart,
    const float* __restrict__ wo, const float* __restrict__ bo,
    float* __restrict__ out)
{
    const int n0 = blockIdx.x * 64;
    const int mhalf = blockIdx.y;
    const int t = threadIdx.x;

    __shared__ unsigned short Ys[64][264];  // [n][c], pitch 264

    const float* O0 = Opart;
    const float* O1 = Opart + (size_t)CIN * NV;
    const float* L0 = Lpart;
    const float* L1 = Lpart + (size_t)NHEAD * NV;

    {
        const int n = t & 63, cg = t >> 6;
#pragma unroll 4
        for (int cc = 0; cc < 64; cc += 2) {
            const int c = cg * 64 + cc;
            const int h = c >> 5;
            size_t off = (size_t)c * NV + n0 + n;
            size_t loff = (size_t)h * NV + n0 + n;
            float rl = __builtin_amdgcn_rcpf(L0[loff] + L1[loff]);
            float y0 = (O0[off] + O1[off]) * rl + x[off];
            float y1 = (O0[off + NV] + O1[off + NV]) * rl + x[off + NV];
            *(unsigned*)&Ys[n][c] = pk_bf2(y0, y1);
        }
    }
    __syncthreads();

    const int w = t >> 6;
    const int lane = t & 63;
    const int ln = lane & 15;
    const int quad = lane >> 4;

    for (int mt = 0; mt < 4; ++mt) {
        const int m0 = (mhalf * 4 + mt) * 64;
        const int M = m0 + w * 16 + ln;

        f32x4 acc[4] = {};
        for (int k0 = 0; k0 < 256; k0 += 32) {
            float4 a0 = *(const float4*)&wo[(size_t)M * 256 + k0 + quad * 8];
            float4 a1 = *(const float4*)&wo[(size_t)M * 256 + k0 + quad * 8 + 4];
            short8 a;
            unsigned* au = (unsigned*)&a;
            au[0] = pk_bf2(a0.x, a0.y);
            au[1] = pk_bf2(a0.z, a0.w);
            au[2] = pk_bf2(a1.x, a1.y);
            au[3] = pk_bf2(a1.z, a1.w);
            short8 b[4];
#pragma unroll
            for (int nt = 0; nt < 4; ++nt)
                b[nt] = *(const short8*)&Ys[nt * 16 + ln][k0 + quad * 8];
#pragma unroll
            for (int nt = 0; nt < 4; ++nt)
                acc[nt] = __builtin_amdgcn_mfma_f32_16x16x32_bf16(
                    a, b[nt], acc[nt], 0, 0, 0);
        }

        const int mb = m0 + w * 16 + quad * 4;
        float bias[4];
#pragma unroll
        for (int r = 0; r < 4; ++r) bias[r] = bo[mb + r];
#pragma unroll
        for (int nt = 0; nt < 4; ++nt)
#pragma unroll
            for (int r = 0; r < 4; ++r)
                out[(size_t)(mb + r) * NV + n0 + nt * 16 + ln] =
                    acc[nt][r] + bias[r];
    }
}

// ---------------------------------------------------------------------------
extern "C" void kernel_launch(void* const* d_in, const int* in_sizes, int n_in,
                              void* d_out, int out_size, void* d_ws,
                              size_t ws_size, hipStream_t stream)
{
    const float* x  = (const float*)d_in[0];
    const float* wq = (const float*)d_in[1];
    const float* bq = (const float*)d_in[2];
    const float* wk = (const float*)d_in[3];
    const float* bk = (const float*)d_in[4];
    const float* wv = (const float*)d_in[5];
    const float* bv = (const float*)d_in[6];
    const float* wo = (const float*)d_in[7];
    const float* bo = (const float*)d_in[8];
    float* out = (float*)d_out;

    unsigned short* Qbf = (unsigned short*)d_ws;             // 2MB
    unsigned short* Kbf = Qbf + (size_t)CIN * NV;            // 2MB
    unsigned short* Vbf = Kbf + (size_t)CIN * NV;            // 2MB
    float* Lpart = (float*)(Vbf + (size_t)CIN * NV);         // 0.25MB
    float* Opart = Lpart + 2 * (size_t)NHEAD * NV;           // 8MB

    qkv_fused<<<dim3(NV / 64, 3), 256, 0, stream>>>(
        x, wq, bq, wk, bk, wv, bv, Qbf, Kbf, Vbf);
    attn_mfma<<<dim3(NV / 64, NHEAD, NSPLIT), 256, 0, stream>>>(
        Qbf, Kbf, Vbf, Opart, Lpart);
    out_fused<<<dim3(NV / 64, 2), 256, 0, stream>>>(
        x, Opart, Lpart, wo, bo, out);
}

// Round 9
// 139.644 us; speedup vs baseline: 1.0938x; 1.0938x over previous
//
#include <hip/hip_runtime.h>
#include <hip/hip_bf16.h>

#define CIN 256
#define NV 4096
#define NHEAD 8
#define HD 32
#define NSPLIT 2
#define KSPAN (NV / NSPLIT)
#define LOG2E 1.44269504088896340736f
#define LOG2_10K_16 0.8304820237218405f  /* log2(10000)/16 */

typedef __attribute__((ext_vector_type(8))) short short8;
typedef __attribute__((ext_vector_type(4))) float f32x4;

static __device__ __forceinline__ unsigned short f2bf(float f) {
    union { float f; unsigned u; } v; v.f = f;
    unsigned r = v.u + 0x7fffu + ((v.u >> 16) & 1u);  // RNE
    return (unsigned short)(r >> 16);
}
// pack two fp32 -> packed bf16 pair (truncating): lo from x0, hi from x1
static __device__ __forceinline__ unsigned pk_bf2(float x0, float x1) {
    return __builtin_amdgcn_perm(__float_as_uint(x1), __float_as_uint(x0),
                                 0x07060302u);
}

// ---------------------------------------------------------------------------
// Kernel 1: QKV projection. 32-wide n-tiles for high block count (1536 blocks,
// ~6/CU): short staging phase (32x256 x-transpose -> LDS bf16), one 64-row
// m-tile per block. Weights converted fp32->bf16 inline in the A-fragment.
//   Q,K -> [h][n][c] bf16 (Q pre-scaled by log2e) ; V -> [c][n] bf16
// grid (NV/32, 4, 3), block 256.
// ---------------------------------------------------------------------------
__global__ __launch_bounds__(256) void qkv_fused(
    const float* __restrict__ x,
    const float* __restrict__ wq, const float* __restrict__ bq,
    const float* __restrict__ wk, const float* __restrict__ bk,
    const float* __restrict__ wv, const float* __restrict__ bv,
    unsigned short* __restrict__ Qbf, unsigned short* __restrict__ Kbf,
    unsigned short* __restrict__ Vbf)
{
    const int which = blockIdx.z;
    const float* Wp = (which == 0) ? wq : (which == 1) ? wk : wv;
    const float* Bp = (which == 0) ? bq : (which == 1) ? bk : bv;
    const int cbase = (which == 0) ? 0 : CIN;

    const int n0 = blockIdx.x * 32;
    const int m0 = blockIdx.y * 64;
    const int t = threadIdx.x;

    __shared__ unsigned short Xs[32][264];  // [n][c], pitch 264 (16B mult)

    // stage: x [c][n] fp32 -> Xs [n][c] bf16 (coalesced 32-lane reads)
    {
        const int n = t & 31, cg = t >> 5;  // 8 channel-groups of 32
#pragma unroll 4
        for (int cc = 0; cc < 32; cc += 2) {
            const int c = cg * 32 + cc;
            size_t off = (size_t)(cbase + c) * NV + n0 + n;
            *(unsigned*)&Xs[n][c] = pk_bf2(x[off], x[off + NV]);
        }
    }
    __syncthreads();

    const int w = t >> 6;
    const int lane = t & 63;
    const int ln = lane & 15;
    const int quad = lane >> 4;
    const int M = m0 + w * 16 + ln;

    f32x4 acc[2] = {};
    for (int k0 = 0; k0 < 256; k0 += 32) {
        float4 a0 = *(const float4*)&Wp[(size_t)M * 256 + k0 + quad * 8];
        float4 a1 = *(const float4*)&Wp[(size_t)M * 256 + k0 + quad * 8 + 4];
        short8 a;
        unsigned* au = (unsigned*)&a;
        au[0] = pk_bf2(a0.x, a0.y);
        au[1] = pk_bf2(a0.z, a0.w);
        au[2] = pk_bf2(a1.x, a1.y);
        au[3] = pk_bf2(a1.z, a1.w);
        short8 b[2];
#pragma unroll
        for (int nt = 0; nt < 2; ++nt)
            b[nt] = *(const short8*)&Xs[nt * 16 + ln][k0 + quad * 8];
        if (which == 2) {
#pragma unroll
            for (int nt = 0; nt < 2; ++nt)
                acc[nt] = __builtin_amdgcn_mfma_f32_16x16x32_bf16(
                    b[nt], a, acc[nt], 0, 0, 0);
        } else {
#pragma unroll
            for (int nt = 0; nt < 2; ++nt)
                acc[nt] = __builtin_amdgcn_mfma_f32_16x16x32_bf16(
                    a, b[nt], acc[nt], 0, 0, 0);
        }
    }

    if (which == 2) {
        // lane holds V[n=n0+nt*16+quad*4+r][ch=m0+w*16+ln]
        const int ch = m0 + w * 16 + ln;
        const float bias = Bp[ch];
#pragma unroll
        for (int nt = 0; nt < 2; ++nt) {
            unsigned short pk[4];
#pragma unroll
            for (int r = 0; r < 4; ++r) pk[r] = f2bf(acc[nt][r] + bias);
            *(uint2*)&Vbf[(size_t)ch * NV + n0 + nt * 16 + quad * 4] =
                *(uint2*)pk;
        }
    } else {
        // lane holds D[m=m0+w*16+quad*4+r][n=n0+nt*16+ln]; RoPE + 4-ch pack
        unsigned short* dst = (which == 0) ? Qbf : Kbf;
        const int mb = m0 + w * 16 + quad * 4;
        const int h = mb >> 5;
        const int cb = mb & 31;
        const float qscale = (which == 0) ? LOG2E : 1.0f;
        float bias[4], invf[4];
#pragma unroll
        for (int r = 0; r < 4; ++r) {
            bias[r] = Bp[mb + r];
            invf[r] = __builtin_amdgcn_exp2f(
                -(float)((cb + r) & 15) * LOG2_10K_16);
        }
        const bool use_sin = (cb < 16);
#pragma unroll
        for (int nt = 0; nt < 2; ++nt) {
            const int n = n0 + nt * 16 + ln;
            const float pos = (float)n * (2.0f / 4095.0f) - 1.0f;
            unsigned short pk[4];
#pragma unroll
            for (int r = 0; r < 4; ++r) {
                float ang = pos * invf[r];
                float f = (use_sin ? __sinf(ang) : __cosf(ang)) * qscale;
                pk[r] = f2bf((acc[nt][r] + bias[r]) * f);
            }
            *(uint2*)&dst[((size_t)h * NV + n) * HD + cb] = *(uint2*)pk;
        }
    }
}

// ---------------------------------------------------------------------------
// Kernel 2: attention (unchanged from round 8). bf16 MFMA, split-K,
// register-resident P, async double-buffered V staging, ones-MFMA
// denominators, raw v_exp (Q log2e-pre-scaled).
// grid (NV/64, NHEAD, NSPLIT), block 256.
// ---------------------------------------------------------------------------
__global__ __launch_bounds__(256, 4) void attn_mfma(
    const unsigned short* __restrict__ Qbf,
    const unsigned short* __restrict__ Kbf,
    const unsigned short* __restrict__ Vbf,
    float* __restrict__ Opart, float* __restrict__ Lpart)
{
    const int h = blockIdx.y;
    const int q0 = blockIdx.x * 64;
    const int z = blockIdx.z;
    const int kbase = z * KSPAN;
    const int t = threadIdx.x;
    const int w = t >> 6;
    const int lane = t & 63;
    const int ln = lane & 15;
    const int quad = lane >> 4;

    __shared__ __align__(16) unsigned short Vs[2][2048];  // 2 x 4KB V tiles

    const short8 qa = *(const short8*)
        &Qbf[((size_t)h * NV + q0 + w * 16 + ln) * HD + quad * 8];

    const unsigned short* Kh = Kbf + (size_t)h * NV * HD;
    const unsigned short* Vh = Vbf + (size_t)h * HD * NV;

    const int c_st = (w << 3) + (lane >> 3);
    const int gr_st = (lane & 7) ^ (c_st & 7);
    const unsigned short* gsrc = Vh + (size_t)c_st * NV + gr_st * 8;
    unsigned short* lds0 = &Vs[0][(size_t)(w * 64 + lane) * 8];
    unsigned short* lds1 = &Vs[1][(size_t)(w * 64 + lane) * 8];

    f32x4 oacc[2] = {};
    f32x4 lacc = {};
    const short vone = (short)0x3F80;
    const short8 vones = {vone, vone, vone, vone, vone, vone, vone, vone};

    __builtin_amdgcn_global_load_lds(
        (const __attribute__((address_space(1))) unsigned int*)(gsrc + kbase),
        (__attribute__((address_space(3))) unsigned int*)lds0, 16, 0, 0);
    short8 kf[4];
#pragma unroll
    for (int ct = 0; ct < 4; ++ct)
        kf[ct] = *(const short8*)
            &Kh[(size_t)(kbase + ct * 16 + ln) * HD + quad * 8];
    __syncthreads();

    for (int i = 0; i < KSPAN / 64; ++i) {
        const int kb = kbase + i * 64;
        const int buf = i & 1;

        if (i + 1 < KSPAN / 64) {
            __builtin_amdgcn_global_load_lds(
                (const __attribute__((address_space(1))) unsigned int*)(gsrc + kb + 64),
                (__attribute__((address_space(3))) unsigned int*)(buf ? lds0 : lds1),
                16, 0, 0);
        }
        const int kbn = kbase + (((i + 1) & (KSPAN / 64 - 1)) * 64);
        short8 kfn[4];
#pragma unroll
        for (int ct = 0; ct < 4; ++ct)
            kfn[ct] = *(const short8*)
                &Kh[(size_t)(kbn + ct * 16 + ln) * HD + quad * 8];

        // S^T: lane holds S'[q=ln][key = kb + 16ct + quad*4 + r] (log2-scaled)
        f32x4 s[4];
#pragma unroll
        for (int ct = 0; ct < 4; ++ct) {
            f32x4 z4 = {0.f, 0.f, 0.f, 0.f};
            s[ct] = __builtin_amdgcn_mfma_f32_16x16x32_bf16(kf[ct], qa, z4,
                                                            0, 0, 0);
        }

        float p[4][4];
#pragma unroll
        for (int ct = 0; ct < 4; ++ct)
#pragma unroll
            for (int r = 0; r < 4; ++r)
                p[ct][r] = __builtin_amdgcn_exp2f(s[ct][r]);

#pragma unroll
        for (int h2 = 0; h2 < 2; ++h2) {
            short8 pa;
            unsigned* pau = (unsigned*)&pa;
            pau[0] = pk_bf2(p[2 * h2][0], p[2 * h2][1]);
            pau[1] = pk_bf2(p[2 * h2][2], p[2 * h2][3]);
            pau[2] = pk_bf2(p[2 * h2 + 1][0], p[2 * h2 + 1][1]);
            pau[3] = pk_bf2(p[2 * h2 + 1][2], p[2 * h2 + 1][3]);
            // denominators: rowsum(P) with the SAME packed weights
            lacc = __builtin_amdgcn_mfma_f32_16x16x32_bf16(pa, vones, lacc,
                                                           0, 0, 0);
#pragma unroll
            for (int ctile = 0; ctile < 2; ++ctile) {
                const int cA = ctile * 16 + ln;
                short8 vb;
                unsigned* vbu = (unsigned*)&vb;
#pragma unroll
                for (int g = 0; g < 2; ++g) {
                    const int gr = h2 * 4 + g * 2 + (quad >> 1);
                    const int sg = gr ^ (ln & 7);
                    uint2 vv = *(const uint2*)
                        &Vs[buf][cA * 64 + sg * 8 + (quad & 1) * 4];
                    vbu[g * 2 + 0] = vv.x;
                    vbu[g * 2 + 1] = vv.y;
                }
                oacc[ctile] = __builtin_amdgcn_mfma_f32_16x16x32_bf16(
                    pa, vb, oacc[ctile], 0, 0, 0);
            }
        }

#pragma unroll
        for (int ct = 0; ct < 4; ++ct) kf[ct] = kfn[ct];
        __syncthreads();
    }

    float* Oz = Opart + (size_t)z * CIN * NV;
    float* Lz = Lpart + (size_t)z * NHEAD * NV;
    if (ln == 0) {
#pragma unroll
        for (int r = 0; r < 4; ++r)
            Lz[(size_t)h * NV + q0 + w * 16 + quad * 4 + r] = lacc[r];
    }
#pragma unroll
    for (int ctile = 0; ctile < 2; ++ctile)
        *(f32x4*)&Oz[(size_t)(h * HD + ctile * 16 + ln) * NV + q0 + w * 16 +
                     quad * 4] = oacc[ctile];
}

// ---------------------------------------------------------------------------
// Kernel 3: fused combine + output projection, 32-wide n-tiles (1024 blocks).
//   Y[n][c] = (O0+O1)[c][n]/(l0+l1) + qf[c][n]  (bf16, LDS), then
//   out = Wo(inline-converted) @ Y + bo for one 64-row m-tile.
// grid (NV/32, 8), block 256.
// ---------------------------------------------------------------------------
__global__ __launch_bounds__(256) void out_fused(
    const float* __restrict__ x,
    const float* __restrict__ Opart, const float* __restrict__ Lpart,
    const float* __restrict__ wo, const float* __restrict__ bo,
    float* __restrict__ out)
{
    const int n0 = blockIdx.x * 32;
    const int m0 = blockIdx.y * 64;
    const int t = threadIdx.x;

    __shared__ unsigned short Ys[32][264];  // [n][c], pitch 264

    const float* O0 = Opart;
    const float* O1 = Opart + (size_t)CIN * NV;
    const float* L0 = Lpart;
    const float* L1 = Lpart + (size_t)NHEAD * NV;

    {
        const int n = t & 31, cg = t >> 5;  // cg = head index (32 ch/head)
        const size_t loff = (size_t)cg * NV + n0 + n;
        const float rl = __builtin_amdgcn_rcpf(L0[loff] + L1[loff]);
#pragma unroll 4
        for (int cc = 0; cc < 32; cc += 2) {
            const int c = cg * 32 + cc;
            size_t off = (size_t)c * NV + n0 + n;
            float y0 = (O0[off] + O1[off]) * rl + x[off];
            float y1 = (O0[off + NV] + O1[off + NV]) * rl + x[off + NV];
            *(unsigned*)&Ys[n][c] = pk_bf2(y0, y1);
        }
    }
    __syncthreads();

    const int w = t >> 6;
    const int lane = t & 63;
    const int ln = lane & 15;
    const int quad = lane >> 4;
    const int M = m0 + w * 16 + ln;

    f32x4 acc[2] = {};
    for (int k0 = 0; k0 < 256; k0 += 32) {
        float4 a0 = *(const float4*)&wo[(size_t)M * 256 + k0 + quad * 8];
        float4 a1 = *(const float4*)&wo[(size_t)M * 256 + k0 + quad * 8 + 4];
        short8 a;
        unsigned* au = (unsigned*)&a;
        au[0] = pk_bf2(a0.x, a0.y);
        au[1] = pk_bf2(a0.z, a0.w);
        au[2] = pk_bf2(a1.x, a1.y);
        au[3] = pk_bf2(a1.z, a1.w);
        short8 b[2];
#pragma unroll
        for (int nt = 0; nt < 2; ++nt)
            b[nt] = *(const short8*)&Ys[nt * 16 + ln][k0 + quad * 8];
#pragma unroll
        for (int nt = 0; nt < 2; ++nt)
            acc[nt] = __builtin_amdgcn_mfma_f32_16x16x32_bf16(
                a, b[nt], acc[nt], 0, 0, 0);
    }

    const int mb = m0 + w * 16 + quad * 4;
    float bias[4];
#pragma unroll
    for (int r = 0; r < 4; ++r) bias[r] = bo[mb + r];
#pragma unroll
    for (int nt = 0; nt < 2; ++nt)
#pragma unroll
        for (int r = 0; r < 4; ++r)
            out[(size_t)(mb + r) * NV + n0 + nt * 16 + ln] =
                acc[nt][r] + bias[r];
}

// ---------------------------------------------------------------------------
extern "C" void kernel_launch(void* const* d_in, const int* in_sizes, int n_in,
                              void* d_out, int out_size, void* d_ws,
                              size_t ws_size, hipStream_t stream)
{
    const float* x  = (const float*)d_in[0];
    const float* wq = (const float*)d_in[1];
    const float* bq = (const float*)d_in[2];
    const float* wk = (const float*)d_in[3];
    const float* bk = (const float*)d_in[4];
    const float* wv = (const float*)d_in[5];
    const float* bv = (const float*)d_in[6];
    const float* wo = (const float*)d_in[7];
    const float* bo = (const float*)d_in[8];
    float* out = (float*)d_out;

    unsigned short* Qbf = (unsigned short*)d_ws;             // 2MB
    unsigned short* Kbf = Qbf + (size_t)CIN * NV;            // 2MB
    unsigned short* Vbf = Kbf + (size_t)CIN * NV;            // 2MB
    float* Lpart = (float*)(Vbf + (size_t)CIN * NV);         // 0.25MB
    float* Opart = Lpart + 2 * (size_t)NHEAD * NV;           // 8MB

    qkv_fused<<<dim3(NV / 32, 4, 3), 256, 0, stream>>>(
        x, wq, bq, wk, bk, wv, bv, Qbf, Kbf, Vbf);
    attn_mfma<<<dim3(NV / 64, NHEAD, NSPLIT), 256, 0, stream>>>(
        Qbf, Kbf, Vbf, Opart, Lpart);
    out_fused<<<dim3(NV / 32, 8), 256, 0, stream>>>(
        x, Opart, Lpart, wo, bo, out);
}

// Round 10
// 129.000 us; speedup vs baseline: 1.1841x; 1.0825x over previous
//
#include <hip/hip_runtime.h>
#include <hip/hip_bf16.h>

#define CIN 256
#define NV 4096
#define NHEAD 8
#define HD 32
#define NSPLIT 2
#define KSPAN (NV / NSPLIT)
#define LOG2E 1.44269504088896340736f
#define LOG2_10K_16 0.8304820237218405f  /* log2(10000)/16 */

typedef __attribute__((ext_vector_type(8))) short short8;
typedef __attribute__((ext_vector_type(4))) float f32x4;

static __device__ __forceinline__ unsigned short f2bf(float f) {
    union { float f; unsigned u; } v; v.f = f;
    unsigned r = v.u + 0x7fffu + ((v.u >> 16) & 1u);  // RNE
    return (unsigned short)(r >> 16);
}
// pack two fp32 -> packed bf16 pair (truncating): lo from x0, hi from x1
static __device__ __forceinline__ unsigned pk_bf2(float x0, float x1) {
    return __builtin_amdgcn_perm(__float_as_uint(x1), __float_as_uint(x0),
                                 0x07060302u);
}
static __device__ __forceinline__ float bflo(unsigned u) {
    return __uint_as_float(u << 16);
}
static __device__ __forceinline__ float bfhi(unsigned u) {
    return __uint_as_float(u & 0xffff0000u);
}

// ---------------------------------------------------------------------------
// Kernel 0: convert all weights to bf16 once. Wb = Wq|Wk|Wv|Wo, 327680 elems.
// ---------------------------------------------------------------------------
__global__ __launch_bounds__(256) void conv_w(
    const float* __restrict__ wq, const float* __restrict__ wk,
    const float* __restrict__ wv, const float* __restrict__ wo,
    unsigned short* __restrict__ Wb)
{
    int i = (blockIdx.x * 256 + threadIdx.x) * 4;
    if (i >= 327680) return;
    const float* src;
    int off = i;
    if (i < 65536) { src = wq; }
    else if (i < 131072) { src = wk; off = i - 65536; }
    else if (i < 196608) { src = wv; off = i - 131072; }
    else { src = wo; off = i - 196608; }
    float4 v = *(const float4*)&src[off];
    unsigned short pk[4] = {f2bf(v.x), f2bf(v.y), f2bf(v.z), f2bf(v.w)};
    *(uint2*)&Wb[i] = *(uint2*)pk;
}

// ---------------------------------------------------------------------------
// Kernel 1: QKV projection. 512-thread blocks, N=64 x M=128 tiles,
// grid (64, 2, 3) = 384 blocks. Stages x-transpose bf16 in LDS once; bf16
// MFMA with direct Wb fragments; epilogue transposes through LDS so ALL
// global stores are full-line coalesced.
//   Q,K -> [h][n][c] (Q pre-scaled by log2e) ; V -> [c][n]
// ---------------------------------------------------------------------------
__global__ __launch_bounds__(512) void qkv_fused(
    const float* __restrict__ x, const unsigned short* __restrict__ Wb,
    const float* __restrict__ bq, const float* __restrict__ bk,
    const float* __restrict__ bv,
    unsigned short* __restrict__ Qbf, unsigned short* __restrict__ Kbf,
    unsigned short* __restrict__ Vbf)
{
    const int which = blockIdx.z;
    const unsigned short* Wp = Wb + (size_t)which * 65536;
    const float* Bp = (which == 0) ? bq : (which == 1) ? bk : bv;
    const int cbase = (which == 0) ? 0 : CIN;

    const int n0 = blockIdx.x * 64;
    const int m0 = blockIdx.y * 128;
    const int t = threadIdx.x;

    __shared__ __align__(16) unsigned short Sbuf[128 * 136];  // 34.8 KB

    // stage x [c][n] fp32 -> Xs[n][c] bf16 (Xs view: row n, pitch 264)
    {
        const int n = t & 63, cg = t >> 6;  // 8 groups x 32 channels
#pragma unroll 4
        for (int cc = 0; cc < 32; cc += 2) {
            const int c = cg * 32 + cc;
            size_t off = (size_t)(cbase + c) * NV + n0 + n;
            *(unsigned*)&Sbuf[n * 264 + c] = pk_bf2(x[off], x[off + NV]);
        }
    }
    __syncthreads();

    const int w = t >> 6;        // 0..7 (8 waves)
    const int lane = t & 63;
    const int ln = lane & 15;
    const int quad = lane >> 4;
    const int M = m0 + w * 16 + ln;

    f32x4 acc[4] = {};
    const unsigned short* Wrow = &Wp[(size_t)M * 256 + quad * 8];
    for (int k0 = 0; k0 < 256; k0 += 32) {
        short8 a = *(const short8*)&Wrow[k0];
        short8 b[4];
#pragma unroll
        for (int nt = 0; nt < 4; ++nt)
            b[nt] = *(const short8*)&Sbuf[(nt * 16 + ln) * 264 + k0 + quad * 8];
        if (which == 2) {
#pragma unroll
            for (int nt = 0; nt < 4; ++nt)
                acc[nt] = __builtin_amdgcn_mfma_f32_16x16x32_bf16(
                    b[nt], a, acc[nt], 0, 0, 0);
        } else {
#pragma unroll
            for (int nt = 0; nt < 4; ++nt)
                acc[nt] = __builtin_amdgcn_mfma_f32_16x16x32_bf16(
                    a, b[nt], acc[nt], 0, 0, 0);
        }
    }
    __syncthreads();  // done reading Xs; reuse Sbuf for epilogue transpose

    if (which == 2) {
        // lane holds V[n = nt*16+quad*4+r][c' = w*16+ln] -> Et2[c'][n] pitch 136
        const int cl = w * 16 + ln;            // local channel 0..127
        const float bias = Bp[m0 + cl];
#pragma unroll
        for (int nt = 0; nt < 4; ++nt) {
            unsigned short pk4[4];
#pragma unroll
            for (int r = 0; r < 4; ++r) pk4[r] = f2bf(acc[nt][r] + bias);
            *(uint2*)&Sbuf[cl * 136 + nt * 16 + quad * 4] = *(uint2*)pk4;
        }
        __syncthreads();
        // coalesced store: 8 lanes cover one 128B row (full lines)
#pragma unroll
        for (int j = 0; j < 2; ++j) {
            int gid = j * 512 + t;
            int n8 = (gid & 7) * 8, cl2 = gid >> 3;  // cl2 0..127
            uint4 v = *(const uint4*)&Sbuf[cl2 * 136 + n8];
            *(uint4*)&Vbf[(size_t)(m0 + cl2) * NV + n0 + n8] = v;
        }
    } else {
        // lane holds D[m = w*16+quad*4+r][n = nt*16+ln]; RoPE then Et[n][m]
        const int mb = m0 + w * 16 + quad * 4;
        const int cb = mb & 31;
        const float qscale = (which == 0) ? LOG2E : 1.0f;
        float bias[4], invf[4];
#pragma unroll
        for (int r = 0; r < 4; ++r) {
            bias[r] = Bp[mb + r];
            invf[r] = __builtin_amdgcn_exp2f(
                -(float)((cb + r) & 15) * LOG2_10K_16);
        }
        const bool use_sin = (cb < 16);
        const int ml = w * 16 + quad * 4;      // local m 0..127
#pragma unroll
        for (int nt = 0; nt < 4; ++nt) {
            const int n = n0 + nt * 16 + ln;
            const float pos = (float)n * (2.0f / 4095.0f) - 1.0f;
#pragma unroll
            for (int r = 0; r < 4; ++r) {
                float ang = pos * invf[r];
                float f = (use_sin ? __sinf(ang) : __cosf(ang)) * qscale;
                Sbuf[(nt * 16 + ln) * 264 + ml + r] =
                    f2bf((acc[nt][r] + bias[r]) * f);
            }
        }
        __syncthreads();
        // coalesced store: fully contiguous 4KB runs per (head, n-range)
        unsigned short* dst = (which == 0) ? Qbf : Kbf;
        const int h0 = m0 >> 5;
#pragma unroll
        for (int j = 0; j < 2; ++j) {
            int gid = j * 512 + t;               // 0..1023
            int c8 = (gid & 3) * 8;              // 0,8,16,24
            int n = (gid >> 2) & 63;
            int hh = gid >> 8;                   // 0..3
            uint4 v = *(const uint4*)&Sbuf[n * 264 + hh * 32 + c8];
            *(uint4*)&dst[((size_t)(h0 + hh) * NV + n0 + n) * HD + c8] = v;
        }
    }
}

// ---------------------------------------------------------------------------
// Kernel 2: attention (identical to round 9 except O stored as bf16).
// grid (NV/64, NHEAD, NSPLIT), block 256.
// ---------------------------------------------------------------------------
__global__ __launch_bounds__(256, 4) void attn_mfma(
    const unsigned short* __restrict__ Qbf,
    const unsigned short* __restrict__ Kbf,
    const unsigned short* __restrict__ Vbf,
    unsigned short* __restrict__ Opartb, float* __restrict__ Lpart)
{
    const int h = blockIdx.y;
    const int q0 = blockIdx.x * 64;
    const int z = blockIdx.z;
    const int kbase = z * KSPAN;
    const int t = threadIdx.x;
    const int w = t >> 6;
    const int lane = t & 63;
    const int ln = lane & 15;
    const int quad = lane >> 4;

    __shared__ __align__(16) unsigned short Vs[2][2048];  // 2 x 4KB V tiles

    const short8 qa = *(const short8*)
        &Qbf[((size_t)h * NV + q0 + w * 16 + ln) * HD + quad * 8];

    const unsigned short* Kh = Kbf + (size_t)h * NV * HD;
    const unsigned short* Vh = Vbf + (size_t)h * HD * NV;

    const int c_st = (w << 3) + (lane >> 3);
    const int gr_st = (lane & 7) ^ (c_st & 7);
    const unsigned short* gsrc = Vh + (size_t)c_st * NV + gr_st * 8;
    unsigned short* lds0 = &Vs[0][(size_t)(w * 64 + lane) * 8];
    unsigned short* lds1 = &Vs[1][(size_t)(w * 64 + lane) * 8];

    f32x4 oacc[2] = {};
    f32x4 lacc = {};
    const short vone = (short)0x3F80;
    const short8 vones = {vone, vone, vone, vone, vone, vone, vone, vone};

    __builtin_amdgcn_global_load_lds(
        (const __attribute__((address_space(1))) unsigned int*)(gsrc + kbase),
        (__attribute__((address_space(3))) unsigned int*)lds0, 16, 0, 0);
    short8 kf[4];
#pragma unroll
    for (int ct = 0; ct < 4; ++ct)
        kf[ct] = *(const short8*)
            &Kh[(size_t)(kbase + ct * 16 + ln) * HD + quad * 8];
    __syncthreads();

    for (int i = 0; i < KSPAN / 64; ++i) {
        const int kb = kbase + i * 64;
        const int buf = i & 1;

        if (i + 1 < KSPAN / 64) {
            __builtin_amdgcn_global_load_lds(
                (const __attribute__((address_space(1))) unsigned int*)(gsrc + kb + 64),
                (__attribute__((address_space(3))) unsigned int*)(buf ? lds0 : lds1),
                16, 0, 0);
        }
        const int kbn = kbase + (((i + 1) & (KSPAN / 64 - 1)) * 64);
        short8 kfn[4];
#pragma unroll
        for (int ct = 0; ct < 4; ++ct)
            kfn[ct] = *(const short8*)
                &Kh[(size_t)(kbn + ct * 16 + ln) * HD + quad * 8];

        // S^T: lane holds S'[q=ln][key = kb + 16ct + quad*4 + r] (log2-scaled)
        f32x4 s[4];
#pragma unroll
        for (int ct = 0; ct < 4; ++ct) {
            f32x4 z4 = {0.f, 0.f, 0.f, 0.f};
            s[ct] = __builtin_amdgcn_mfma_f32_16x16x32_bf16(kf[ct], qa, z4,
                                                            0, 0, 0);
        }

        float p[4][4];
#pragma unroll
        for (int ct = 0; ct < 4; ++ct)
#pragma unroll
            for (int r = 0; r < 4; ++r)
                p[ct][r] = __builtin_amdgcn_exp2f(s[ct][r]);

#pragma unroll
        for (int h2 = 0; h2 < 2; ++h2) {
            short8 pa;
            unsigned* pau = (unsigned*)&pa;
            pau[0] = pk_bf2(p[2 * h2][0], p[2 * h2][1]);
            pau[1] = pk_bf2(p[2 * h2][2], p[2 * h2][3]);
            pau[2] = pk_bf2(p[2 * h2 + 1][0], p[2 * h2 + 1][1]);
            pau[3] = pk_bf2(p[2 * h2 + 1][2], p[2 * h2 + 1][3]);
            // denominators: rowsum(P) with the SAME packed weights
            lacc = __builtin_amdgcn_mfma_f32_16x16x32_bf16(pa, vones, lacc,
                                                           0, 0, 0);
#pragma unroll
            for (int ctile = 0; ctile < 2; ++ctile) {
                const int cA = ctile * 16 + ln;
                short8 vb;
                unsigned* vbu = (unsigned*)&vb;
#pragma unroll
                for (int g = 0; g < 2; ++g) {
                    const int gr = h2 * 4 + g * 2 + (quad >> 1);
                    const int sg = gr ^ (ln & 7);
                    uint2 vv = *(const uint2*)
                        &Vs[buf][cA * 64 + sg * 8 + (quad & 1) * 4];
                    vbu[g * 2 + 0] = vv.x;
                    vbu[g * 2 + 1] = vv.y;
                }
                oacc[ctile] = __builtin_amdgcn_mfma_f32_16x16x32_bf16(
                    pa, vb, oacc[ctile], 0, 0, 0);
            }
        }

#pragma unroll
        for (int ct = 0; ct < 4; ++ct) kf[ct] = kfn[ct];
        __syncthreads();
    }

    unsigned short* Oz = Opartb + (size_t)z * CIN * NV;
    float* Lz = Lpart + (size_t)z * NHEAD * NV;
    if (ln == 0) {
#pragma unroll
        for (int r = 0; r < 4; ++r)
            Lz[(size_t)h * NV + q0 + w * 16 + quad * 4 + r] = lacc[r];
    }
#pragma unroll
    for (int ctile = 0; ctile < 2; ++ctile) {
        uint2 st;
        st.x = pk_bf2(oacc[ctile][0], oacc[ctile][1]);
        st.y = pk_bf2(oacc[ctile][2], oacc[ctile][3]);
        *(uint2*)&Oz[(size_t)(h * HD + ctile * 16 + ln) * NV + q0 + w * 16 +
                     quad * 4] = st;
    }
}

// ---------------------------------------------------------------------------
// Kernel 3: fused combine + output projection. 512-thread blocks, N=64 x
// M=128, grid (64, 4) = 256 blocks. O partials read as bf16; Wo bf16 direct.
//   Y[n][c] = (O0+O1)[c][n]/(l0+l1) + qf[c][n];  out = Wo @ Y + bo
// ---------------------------------------------------------------------------
__global__ __launch_bounds__(512) void out_fused(
    const float* __restrict__ x,
    const unsigned short* __restrict__ O0b,
    const unsigned short* __restrict__ O1b,
    const float* __restrict__ Lpart,
    const unsigned short* __restrict__ Wob, const float* __restrict__ bo,
    float* __restrict__ out)
{
    const int n0 = blockIdx.x * 64;
    const int m0 = blockIdx.y * 128;
    const int t = threadIdx.x;

    __shared__ __align__(16) unsigned short Ys[64 * 264];  // 33.8 KB

    const float* L0 = Lpart;
    const float* L1 = Lpart + (size_t)NHEAD * NV;

    {
        const int n2 = (t & 31) * 2;
        const int grp = t >> 5;                 // 0..15 (16 channels each)
        const int h = grp >> 1;                 // head constant per thread
        const size_t lo = (size_t)h * NV + n0 + n2;
        const float rl0 = __builtin_amdgcn_rcpf(L0[lo] + L1[lo]);
        const float rl1 = __builtin_amdgcn_rcpf(L0[lo + 1] + L1[lo + 1]);
#pragma unroll 4
        for (int i = 0; i < 16; ++i) {
            const int c = grp * 16 + i;
            size_t off = (size_t)c * NV + n0 + n2;
            unsigned o0 = *(const unsigned*)&O0b[off];
            unsigned o1 = *(const unsigned*)&O1b[off];
            float2 x2 = *(const float2*)&x[off];
            float y0 = (bflo(o0) + bflo(o1)) * rl0 + x2.x;
            float y1 = (bfhi(o0) + bfhi(o1)) * rl1 + x2.y;
            Ys[n2 * 264 + c] = f2bf(y0);
            Ys[(n2 + 1) * 264 + c] = f2bf(y1);
        }
    }
    __syncthreads();

    const int w = t >> 6;        // 0..7
    const int lane = t & 63;
    const int ln = lane & 15;
    const int quad = lane >> 4;
    const int M = m0 + w * 16 + ln;

    const unsigned short* Wrow = &Wob[(size_t)M * 256 + quad * 8];
    f32x4 acc[4] = {};
    for (int k0 = 0; k0 < 256; k0 += 32) {
        short8 a = *(const short8*)&Wrow[k0];
        short8 b[4];
#pragma unroll
        for (int nt = 0; nt < 4; ++nt)
            b[nt] = *(const short8*)&Ys[(nt * 16 + ln) * 264 + k0 + quad * 8];
#pragma unroll
        for (int nt = 0; nt < 4; ++nt)
            acc[nt] = __builtin_amdgcn_mfma_f32_16x16x32_bf16(
                a, b[nt], acc[nt], 0, 0, 0);
    }

    const int mb = m0 + w * 16 + quad * 4;
    float bias[4];
#pragma unroll
    for (int r = 0; r < 4; ++r) bias[r] = bo[mb + r];
#pragma unroll
    for (int nt = 0; nt < 4; ++nt)
#pragma unroll
        for (int r = 0; r < 4; ++r)
            out[(size_t)(mb + r) * NV + n0 + nt * 16 + ln] =
                acc[nt][r] + bias[r];
}

// ---------------------------------------------------------------------------
extern "C" void kernel_launch(void* const* d_in, const int* in_sizes, int n_in,
                              void* d_out, int out_size, void* d_ws,
                              size_t ws_size, hipStream_t stream)
{
    const float* x  = (const float*)d_in[0];
    const float* wq = (const float*)d_in[1];
    const float* bq = (const float*)d_in[2];
    const float* wk = (const float*)d_in[3];
    const float* bk = (const float*)d_in[4];
    const float* wv = (const float*)d_in[5];
    const float* bv = (const float*)d_in[6];
    const float* wo = (const float*)d_in[7];
    const float* bo = (const float*)d_in[8];
    float* out = (float*)d_out;

    unsigned short* Wb  = (unsigned short*)d_ws;            // 655 KB bf16
    unsigned short* Qbf = Wb + 327680;                      // 2MB
    unsigned short* Kbf = Qbf + (size_t)CIN * NV;           // 2MB
    unsigned short* Vbf = Kbf + (size_t)CIN * NV;           // 2MB
    float* Lpart = (float*)(Vbf + (size_t)CIN * NV);        // 256KB
    unsigned short* Opartb =
        (unsigned short*)(Lpart + 2 * (size_t)NHEAD * NV);  // 4MB (2 splits)

    conv_w<<<dim3(320), 256, 0, stream>>>(wq, wk, wv, wo, Wb);
    qkv_fused<<<dim3(64, 2, 3), 512, 0, stream>>>(
        x, Wb, bq, bk, bv, Qbf, Kbf, Vbf);
    attn_mfma<<<dim3(NV / 64, NHEAD, NSPLIT), 256, 0, stream>>>(
        Qbf, Kbf, Vbf, Opartb, Lpart);
    out_fused<<<dim3(64, 4), 512, 0, stream>>>(
        x, Opartb, Opartb + (size_t)CIN * NV, Lpart, Wb + 196608, bo, out);
}

// Round 11
// 120.536 us; speedup vs baseline: 1.2672x; 1.0702x over previous
//
#include <hip/hip_runtime.h>
#include <hip/hip_bf16.h>

#define CIN 256
#define NV 4096
#define NHEAD 8
#define HD 32
#define NSPLIT 4
#define KSPAN (NV / NSPLIT)
#define LOG2E 1.44269504088896340736f
#define LOG2_10K_16 0.8304820237218405f  /* log2(10000)/16 */

typedef __attribute__((ext_vector_type(8))) short short8;
typedef __attribute__((ext_vector_type(4))) float f32x4;

static __device__ __forceinline__ unsigned short f2bf(float f) {
    union { float f; unsigned u; } v; v.f = f;
    unsigned r = v.u + 0x7fffu + ((v.u >> 16) & 1u);  // RNE
    return (unsigned short)(r >> 16);
}
// pack two fp32 -> packed bf16 pair (truncating): lo from x0, hi from x1
static __device__ __forceinline__ unsigned pk_bf2(float x0, float x1) {
    return __builtin_amdgcn_perm(__float_as_uint(x1), __float_as_uint(x0),
                                 0x07060302u);
}
static __device__ __forceinline__ float bflo(unsigned u) {
    return __uint_as_float(u << 16);
}
static __device__ __forceinline__ float bfhi(unsigned u) {
    return __uint_as_float(u & 0xffff0000u);
}

// ---------------------------------------------------------------------------
// Kernel 0: convert all weights to bf16 once. Wb = Wq|Wk|Wv|Wo, 327680 elems.
// ---------------------------------------------------------------------------
__global__ __launch_bounds__(256) void conv_w(
    const float* __restrict__ wq, const float* __restrict__ wk,
    const float* __restrict__ wv, const float* __restrict__ wo,
    unsigned short* __restrict__ Wb)
{
    int i = (blockIdx.x * 256 + threadIdx.x) * 4;
    if (i >= 327680) return;
    const float* src;
    int off = i;
    if (i < 65536) { src = wq; }
    else if (i < 131072) { src = wk; off = i - 65536; }
    else if (i < 196608) { src = wv; off = i - 131072; }
    else { src = wo; off = i - 196608; }
    float4 v = *(const float4*)&src[off];
    unsigned short pk[4] = {f2bf(v.x), f2bf(v.y), f2bf(v.z), f2bf(v.w)};
    *(uint2*)&Wb[i] = *(uint2*)pk;
}

// ---------------------------------------------------------------------------
// Kernel 1: QKV projection. 512-thread blocks, N=32 x M=128, grid (128,2,3)
// = 768 blocks (3/CU). x-transpose staged bf16 in LDS once; bf16 MFMA with
// direct Wb fragments; epilogue transposes through LDS -> coalesced stores.
//   Q,K -> [h][n][c] (Q pre-scaled by log2e)
//   V   -> [c][n] with keys PERMUTED within each 32-key half so the attention
//          PV B-fragment is one contiguous 16B LDS read:
//          pos q*8 + g*4 + r  holds key g*16 + q*4 + r   (q,g,r in 4,2,4)
// ---------------------------------------------------------------------------
__global__ __launch_bounds__(512) void qkv_fused(
    const float* __restrict__ x, const unsigned short* __restrict__ Wb,
    const float* __restrict__ bq, const float* __restrict__ bk,
    const float* __restrict__ bv,
    unsigned short* __restrict__ Qbf, unsigned short* __restrict__ Kbf,
    unsigned short* __restrict__ Vbf)
{
    const int which = blockIdx.z;
    const unsigned short* Wp = Wb + (size_t)which * 65536;
    const float* Bp = (which == 0) ? bq : (which == 1) ? bk : bv;
    const int cbase = (which == 0) ? 0 : CIN;

    const int n0 = blockIdx.x * 32;
    const int m0 = blockIdx.y * 128;
    const int t = threadIdx.x;

    __shared__ __align__(16) unsigned short Sbuf[32 * 264];  // 16.9 KB

    // stage x [c][n] fp32 -> Xs[n][c] bf16 (row pitch 264)
    {
        const int n = t & 31, cg = t >> 5;  // 16 groups x 16 channels
#pragma unroll 4
        for (int cc = 0; cc < 16; cc += 2) {
            const int c = cg * 16 + cc;
            size_t off = (size_t)(cbase + c) * NV + n0 + n;
            *(unsigned*)&Sbuf[n * 264 + c] = pk_bf2(x[off], x[off + NV]);
        }
    }
    __syncthreads();

    const int w = t >> 6;        // 0..7
    const int lane = t & 63;
    const int ln = lane & 15;
    const int quad = lane >> 4;
    const int M = m0 + w * 16 + ln;

    f32x4 acc[2] = {};
    const unsigned short* Wrow = &Wp[(size_t)M * 256 + quad * 8];
    for (int k0 = 0; k0 < 256; k0 += 32) {
        short8 a = *(const short8*)&Wrow[k0];
        short8 b[2];
#pragma unroll
        for (int nt = 0; nt < 2; ++nt)
            b[nt] = *(const short8*)&Sbuf[(nt * 16 + ln) * 264 + k0 + quad * 8];
        if (which == 2) {
#pragma unroll
            for (int nt = 0; nt < 2; ++nt)
                acc[nt] = __builtin_amdgcn_mfma_f32_16x16x32_bf16(
                    b[nt], a, acc[nt], 0, 0, 0);
        } else {
#pragma unroll
            for (int nt = 0; nt < 2; ++nt)
                acc[nt] = __builtin_amdgcn_mfma_f32_16x16x32_bf16(
                    a, b[nt], acc[nt], 0, 0, 0);
        }
    }
    __syncthreads();  // Xs no longer needed; reuse Sbuf

    if (which == 2) {
        // lane holds V[n = nt*16+quad*4+r][c' = w*16+ln]; Sbuf[c'][key] pitch 40
        const int cl = w * 16 + ln;            // local channel 0..127
        const float bias = Bp[m0 + cl];
#pragma unroll
        for (int nt = 0; nt < 2; ++nt) {
            unsigned short pk4[4];
#pragma unroll
            for (int r = 0; r < 4; ++r) pk4[r] = f2bf(acc[nt][r] + bias);
            *(uint2*)&Sbuf[cl * 40 + nt * 16 + quad * 4] = *(uint2*)pk4;
        }
        __syncthreads();
        // permuted store: out granule q holds keys {q*4+0..3, 16+q*4+0..3}
        {
            const int cl2 = t >> 2, q = t & 3;
            uint2 lo = *(const uint2*)&Sbuf[cl2 * 40 + q * 4];
            uint2 hi = *(const uint2*)&Sbuf[cl2 * 40 + 16 + q * 4];
            uint4 v;
            v.x = lo.x; v.y = lo.y; v.z = hi.x; v.w = hi.y;
            *(uint4*)&Vbf[(size_t)(m0 + cl2) * NV + n0 + q * 8] = v;
        }
    } else {
        // lane holds D[m = w*16+quad*4+r][n = nt*16+ln]; RoPE, then Et[n][m]
        const int mb = m0 + w * 16 + quad * 4;
        const int cb = mb & 31;
        const float qscale = (which == 0) ? LOG2E : 1.0f;
        float bias[4], invf[4];
#pragma unroll
        for (int r = 0; r < 4; ++r) {
            bias[r] = Bp[mb + r];
            invf[r] = __builtin_amdgcn_exp2f(
                -(float)((cb + r) & 15) * LOG2_10K_16);
        }
        const bool use_sin = (cb < 16);
        const int ml = w * 16 + quad * 4;      // local m 0..127
#pragma unroll
        for (int nt = 0; nt < 2; ++nt) {
            const int n = n0 + nt * 16 + ln;
            const float pos = (float)n * (2.0f / 4095.0f) - 1.0f;
#pragma unroll
            for (int r = 0; r < 4; ++r) {
                float ang = pos * invf[r];
                float f = (use_sin ? __sinf(ang) : __cosf(ang)) * qscale;
                Sbuf[(nt * 16 + ln) * 264 + ml + r] =
                    f2bf((acc[nt][r] + bias[r]) * f);
            }
        }
        __syncthreads();
        // coalesced store: per head 2KB contiguous runs
        unsigned short* dst = (which == 0) ? Qbf : Kbf;
        const int h0 = m0 >> 5;
        {
            const int hh = t >> 7;             // 0..3
            const int n = (t >> 2) & 31;
            const int cw = t & 3;
            uint4 v = *(const uint4*)&Sbuf[n * 264 + hh * 32 + cw * 8];
            *(uint4*)&dst[((size_t)(h0 + hh) * NV + n0 + n) * HD + cw * 8] = v;
        }
    }
}

// ---------------------------------------------------------------------------
// Kernel 2: attention. bf16 MFMA, split-K(4), register-resident P. BOTH K and
// V tiles staged via async global_load_lds (16B), double-buffered, one
// barrier/iter; all fragment reads are single ds_read_b128 (swizzled, 2-way
// = free). Ones-MFMA denominators; Q log2e-pre-scaled -> raw v_exp.
// grid (NV/64, NHEAD, NSPLIT), block 256.
// ---------------------------------------------------------------------------
__global__ __launch_bounds__(256, 4) void attn_mfma(
    const unsigned short* __restrict__ Qbf,
    const unsigned short* __restrict__ Kbf,
    const unsigned short* __restrict__ Vbf,
    unsigned short* __restrict__ Opartb, float* __restrict__ Lpart)
{
    const int h = blockIdx.y;
    const int q0 = blockIdx.x * 64;
    const int z = blockIdx.z;
    const int kbase = z * KSPAN;
    const int t = threadIdx.x;
    const int w = t >> 6;
    const int lane = t & 63;
    const int ln = lane & 15;
    const int quad = lane >> 4;

    // K tile: 64 keys x 32c, row=key (64B, 4 granules, slot = g ^ (key&3))
    // V tile: 32 c x 64 perm-keys, row=c (128B, 8 granules, slot = g ^ (c&7))
    __shared__ __align__(16) unsigned short Ks[2][2048];
    __shared__ __align__(16) unsigned short Vs[2][2048];

    const short8 qa = *(const short8*)
        &Qbf[((size_t)h * NV + q0 + w * 16 + ln) * HD + quad * 8];

    const unsigned short* Kh = Kbf + (size_t)h * NV * HD;
    const unsigned short* Vh = Vbf + (size_t)h * HD * NV;

    // V staging: thread t -> channel t>>3, source granule (t&7)^(c&7)
    const int cv = t >> 3;
    const unsigned short* gsrcV = Vh + (size_t)cv * NV + ((t & 7) ^ (cv & 7)) * 8;
    // K staging: thread t -> key t>>2, source granule (t&3)^(key&3)
    const int kv = t >> 2;
    const unsigned short* gsrcK =
        Kh + (size_t)kv * HD + ((t & 3) ^ (kv & 3)) * 8;

    f32x4 oacc[2] = {};
    f32x4 lacc = {};
    const short vone = (short)0x3F80;
    const short8 vones = {vone, vone, vone, vone, vone, vone, vone, vone};

    __builtin_amdgcn_global_load_lds(
        (const __attribute__((address_space(1))) unsigned int*)(gsrcK +
            (size_t)kbase * HD),
        (__attribute__((address_space(3))) unsigned int*)&Ks[0][t * 8], 16, 0, 0);
    __builtin_amdgcn_global_load_lds(
        (const __attribute__((address_space(1))) unsigned int*)(gsrcV + kbase),
        (__attribute__((address_space(3))) unsigned int*)&Vs[0][t * 8], 16, 0, 0);
    __syncthreads();

    const int sgk = (quad ^ (ln & 3)) * 8;       // K-read swizzled granule
    for (int i = 0; i < KSPAN / 64; ++i) {
        const int kb = kbase + i * 64;
        const int buf = i & 1;

        if (i + 1 < KSPAN / 64) {
            __builtin_amdgcn_global_load_lds(
                (const __attribute__((address_space(1))) unsigned int*)(gsrcK +
                    (size_t)(kb + 64) * HD),
                (__attribute__((address_space(3))) unsigned int*)&Ks[buf ^ 1][t * 8],
                16, 0, 0);
            __builtin_amdgcn_global_load_lds(
                (const __attribute__((address_space(1))) unsigned int*)(gsrcV +
                    kb + 64),
                (__attribute__((address_space(3))) unsigned int*)&Vs[buf ^ 1][t * 8],
                16, 0, 0);
        }

        // S^T: lane holds S'[q=ln][key = kb + 16ct + quad*4 + r]
        f32x4 s[4];
#pragma unroll
        for (int ct = 0; ct < 4; ++ct) {
            const short8 kf = *(const short8*)
                &Ks[buf][(ct * 16 + ln) * 32 + sgk];
            f32x4 z4 = {0.f, 0.f, 0.f, 0.f};
            s[ct] = __builtin_amdgcn_mfma_f32_16x16x32_bf16(kf, qa, z4,
                                                            0, 0, 0);
        }

        float p[4][4];
#pragma unroll
        for (int ct = 0; ct < 4; ++ct)
#pragma unroll
            for (int r = 0; r < 4; ++r)
                p[ct][r] = __builtin_amdgcn_exp2f(s[ct][r]);

#pragma unroll
        for (int h2 = 0; h2 < 2; ++h2) {
            short8 pa;
            unsigned* pau = (unsigned*)&pa;
            pau[0] = pk_bf2(p[2 * h2][0], p[2 * h2][1]);
            pau[1] = pk_bf2(p[2 * h2][2], p[2 * h2][3]);
            pau[2] = pk_bf2(p[2 * h2 + 1][0], p[2 * h2 + 1][1]);
            pau[3] = pk_bf2(p[2 * h2 + 1][2], p[2 * h2 + 1][3]);
            // denominators: rowsum(P) with the SAME packed weights
            lacc = __builtin_amdgcn_mfma_f32_16x16x32_bf16(pa, vones, lacc,
                                                           0, 0, 0);
#pragma unroll
            for (int ctile = 0; ctile < 2; ++ctile) {
                const int cA = ctile * 16 + ln;
                // permuted V: B-frag = one contiguous (swizzled) 16B read
                const short8 vb = *(const short8*)
                    &Vs[buf][cA * 64 + (((h2 * 4 + quad) ^ (cA & 7)) * 8)];
                oacc[ctile] = __builtin_amdgcn_mfma_f32_16x16x32_bf16(
                    pa, vb, oacc[ctile], 0, 0, 0);
            }
        }
        __syncthreads();
    }

    unsigned short* Oz = Opartb + (size_t)z * CIN * NV;
    float* Lz = Lpart + (size_t)z * NHEAD * NV;
    if (ln == 0) {
#pragma unroll
        for (int r = 0; r < 4; ++r)
            Lz[(size_t)h * NV + q0 + w * 16 + quad * 4 + r] = lacc[r];
    }
#pragma unroll
    for (int ctile = 0; ctile < 2; ++ctile) {
        uint2 st;
        st.x = pk_bf2(oacc[ctile][0], oacc[ctile][1]);
        st.y = pk_bf2(oacc[ctile][2], oacc[ctile][3]);
        *(uint2*)&Oz[(size_t)(h * HD + ctile * 16 + ln) * NV + q0 + w * 16 +
                     quad * 4] = st;
    }
}

// ---------------------------------------------------------------------------
// Kernel 3: fused combine + output projection. 512-thread blocks, N=32 x
// M=128, grid (128, 4) = 512 blocks.  Y = (sum_z O_z)/(sum_z l_z) + qf,
// staged bf16 in LDS; out = Wo(bf16) @ Y + bo.
// ---------------------------------------------------------------------------
__global__ __launch_bounds__(512) void out_fused(
    const float* __restrict__ x,
    const unsigned short* __restrict__ Opartb,
    const float* __restrict__ Lpart,
    const unsigned short* __restrict__ Wob, const float* __restrict__ bo,
    float* __restrict__ out)
{
    const int n0 = blockIdx.x * 32;
    const int m0 = blockIdx.y * 128;
    const int t = threadIdx.x;

    __shared__ __align__(16) unsigned short Ys[32 * 264];  // 16.9 KB

    {
        const int n2 = (t & 15) * 2;
        const int grp = t >> 4;                 // 0..31, 8 channels each
        const int h = grp >> 2;                 // head
        const size_t lo = (size_t)h * NV + n0 + n2;
        float l0 = 0.f, l1 = 0.f;
#pragma unroll
        for (int zz = 0; zz < NSPLIT; ++zz) {
            l0 += Lpart[(size_t)zz * NHEAD * NV + lo];
            l1 += Lpart[(size_t)zz * NHEAD * NV + lo + 1];
        }
        const float rl0 = __builtin_amdgcn_rcpf(l0);
        const float rl1 = __builtin_amdgcn_rcpf(l1);
#pragma unroll
        for (int i = 0; i < 8; ++i) {
            const int c = grp * 8 + i;
            size_t off = (size_t)c * NV + n0 + n2;
            float s0 = 0.f, s1 = 0.f;
#pragma unroll
            for (int zz = 0; zz < NSPLIT; ++zz) {
                unsigned o = *(const unsigned*)&Opartb[(size_t)zz * CIN * NV + off];
                s0 += bflo(o);
                s1 += bfhi(o);
            }
            float2 x2 = *(const float2*)&x[off];
            Ys[n2 * 264 + c] = f2bf(s0 * rl0 + x2.x);
            Ys[(n2 + 1) * 264 + c] = f2bf(s1 * rl1 + x2.y);
        }
    }
    __syncthreads();

    const int w = t >> 6;        // 0..7
    const int lane = t & 63;
    const int ln = lane & 15;
    const int quad = lane >> 4;
    const int M = m0 + w * 16 + ln;

    const unsigned short* Wrow = &Wob[(size_t)M * 256 + quad * 8];
    f32x4 acc[2] = {};
    for (int k0 = 0; k0 < 256; k0 += 32) {
        short8 a = *(const short8*)&Wrow[k0];
        short8 b[2];
#pragma unroll
        for (int nt = 0; nt < 2; ++nt)
            b[nt] = *(const short8*)&Ys[(nt * 16 + ln) * 264 + k0 + quad * 8];
#pragma unroll
        for (int nt = 0; nt < 2; ++nt)
            acc[nt] = __builtin_amdgcn_mfma_f32_16x16x32_bf16(
                a, b[nt], acc[nt], 0, 0, 0);
    }

    const int mb = m0 + w * 16 + quad * 4;
    float bias[4];
#pragma unroll
    for (int r = 0; r < 4; ++r) bias[r] = bo[mb + r];
#pragma unroll
    for (int nt = 0; nt < 2; ++nt)
#pragma unroll
        for (int r = 0; r < 4; ++r)
            out[(size_t)(mb + r) * NV + n0 + nt * 16 + ln] =
                acc[nt][r] + bias[r];
}

// ---------------------------------------------------------------------------
extern "C" void kernel_launch(void* const* d_in, const int* in_sizes, int n_in,
                              void* d_out, int out_size, void* d_ws,
                              size_t ws_size, hipStream_t stream)
{
    const float* x  = (const float*)d_in[0];
    const float* wq = (const float*)d_in[1];
    const float* bq = (const float*)d_in[2];
    const float* wk = (const float*)d_in[3];
    const float* bk = (const float*)d_in[4];
    const float* wv = (const float*)d_in[5];
    const float* bv = (const float*)d_in[6];
    const float* wo = (const float*)d_in[7];
    const float* bo = (const float*)d_in[8];
    float* out = (float*)d_out;

    unsigned short* Wb  = (unsigned short*)d_ws;            // 655 KB bf16
    unsigned short* Qbf = Wb + 327680;                      // 2MB
    unsigned short* Kbf = Qbf + (size_t)CIN * NV;           // 2MB
    unsigned short* Vbf = Kbf + (size_t)CIN * NV;           // 2MB
    float* Lpart = (float*)(Vbf + (size_t)CIN * NV);        // 512KB (4 splits)
    unsigned short* Opartb =
        (unsigned short*)(Lpart + NSPLIT * (size_t)NHEAD * NV);  // 8MB

    conv_w<<<dim3(320), 256, 0, stream>>>(wq, wk, wv, wo, Wb);
    qkv_fused<<<dim3(128, 2, 3), 512, 0, stream>>>(
        x, Wb, bq, bk, bv, Qbf, Kbf, Vbf);
    attn_mfma<<<dim3(NV / 64, NHEAD, NSPLIT), 256, 0, stream>>>(
        Qbf, Kbf, Vbf, Opartb, Lpart);
    out_fused<<<dim3(128, 4), 512, 0, stream>>>(
        x, Opartb, Lpart, Wb + 196608, bo, out);
}